// Round 5
// baseline (752.619 us; speedup 1.0000x reference)
//
#include <hip/hip_runtime.h>
#include <stdint.h>

#define DMODEL 2048
#define NH 16
#define HD 128
#define BATCH 4
#define SEQ 2048
#define MTOT (BATCH * SEQ)  // 8192
#define LOG2E 1.44269504088896340736f

typedef __bf16 bf16x8 __attribute__((ext_vector_type(8)));
typedef float floatx4 __attribute__((ext_vector_type(4)));

__device__ __forceinline__ uint16_t f2b(float f) {
    union { float f; uint32_t i; } v; v.f = f;
    uint32_t r = v.i + 0x7fffu + ((v.i >> 16) & 1u);
    return (uint16_t)(r >> 16);
}

// async global->LDS, 16B per lane, wave-uniform LDS base + lane*16
#define GLD16(gp, lp)                                                          \
    __builtin_amdgcn_global_load_lds(                                          \
        (__attribute__((address_space(1))) unsigned int*)(gp),                 \
        (__attribute__((address_space(3))) unsigned int*)(lp), 16, 0, 0)

#define WAITVMC(N) asm volatile("s_waitcnt vmcnt(" #N ")" ::: "memory")
#define WAITLGKM0                                                              \
    do {                                                                       \
        asm volatile("s_waitcnt lgkmcnt(0)" ::: "memory");                     \
        __builtin_amdgcn_sched_barrier(0);                                     \
    } while (0)

// ---------------------------------------------------------------------------
// fp32 -> bf16 elementwise convert. n multiple of 8. grid n/2048.
// ---------------------------------------------------------------------------
__global__ __launch_bounds__(256) void cvt_bf16(const float* __restrict__ in,
                                                uint16_t* __restrict__ out, int n) {
    const int i = (blockIdx.x * 256 + threadIdx.x) * 8;
    if (i >= n) return;
    const float4 a = *(const float4*)(in + i);
    const float4 b = *(const float4*)(in + i + 4);
    uint16_t v[8] __attribute__((aligned(16))) = {
        f2b(a.x), f2b(a.y), f2b(a.z), f2b(a.w),
        f2b(b.x), f2b(b.y), f2b(b.z), f2b(b.w)};
    *(uint4*)(out + i) = *(const uint4*)v;
}

// ---------------------------------------------------------------------------
// Weight transpose+convert: W fp32 [k][n] (2048x2048) -> Wt bf16 [n][k].
// grid (32,32), 64x64 tiles.
// ---------------------------------------------------------------------------
__global__ __launch_bounds__(256) void tr_wf(const float* __restrict__ in,
                                             uint16_t* __restrict__ out) {
    __shared__ float t[64 * 69];  // stride 69: 2-way max bank aliasing (free)
    const int tid = threadIdx.x;
    const int r0 = blockIdx.y * 64, c0 = blockIdx.x * 64;
    const int rr = tid >> 2, c16 = (tid & 3) << 4;
#pragma unroll
    for (int j = 0; j < 4; j++)
        *(float4*)&t[rr * 69 + c16 + j * 4] =
            *(const float4*)(in + (size_t)(r0 + rr) * DMODEL + c0 + c16 + j * 4);
    __syncthreads();
    const int oc = tid >> 2, r16 = (tid & 3) << 4;
    uint16_t v[16] __attribute__((aligned(16)));
#pragma unroll
    for (int j = 0; j < 16; j++) v[j] = f2b(t[(r16 + j) * 69 + oc]);
    uint16_t* o = out + (size_t)(c0 + oc) * DMODEL + r0 + r16;
    *(uint4*)o = *(const uint4*)v;
    *(uint4*)(o + 8) = *(const uint4*)(v + 8);
}

// ---------------------------------------------------------------------------
// 256x256-tile GEMM, BK=64, 8 waves (512 thr), double-buffered LDS (128 KiB),
// DEPTH-2 COUNTED vmcnt PIPELINE: the main loop never drains vmcnt to 0
// (T3+T4; m218: counted-vs-drain0 = +38-73%). Per iteration:
//   vmcnt(8)+barrier        -> retires exactly the K-tile about to be read
//   ds_read frags (kk0+kk1) -> regs
//   lgkmcnt(0)+sched_barrier+barrier -> buffer provably free (all waves)
//   issue stage of tile kt+2 into the freed buffer (8 x global_load_lds)
//   setprio(1) 64 MFMA setprio(0)
// LDS is FRAGMENT-LINEAR: 1KiB block per MFMA fragment, slot = lane. Reads
// (block*1024 + lane*16) and global_load_lds writes (linear) are both
// conflict-free; the fragment permutation lives in the per-lane GLOBAL source
// address (m173 pattern). Tail: final iteration uses vmcnt(0).
// A bf16 [M x 2048], Bt bf16 [2048 x 2048] ([n][k]). grid = (M/256)*8 blocks
// (1-D, %8==0), XCD-bijective swizzle. 1 block/CU.
// mode 0: C bf16 [m][n]; 1: C fp32; 2: C bf16 transposed [n][m] ld=tld.
// ---------------------------------------------------------------------------
__global__ __launch_bounds__(512, 2) void gemm256(const uint16_t* __restrict__ A,
                                                  const uint16_t* __restrict__ Bt,
                                                  const float* __restrict__ bias,
                                                  void* __restrict__ Cout,
                                                  float scale, int mode, int tld) {
    __shared__ __attribute__((aligned(16))) uint16_t As[2][32 * 512];  // 2x32KiB
    __shared__ __attribute__((aligned(16))) uint16_t Bs[2][32 * 512];  // 2x32KiB

    const int tid = threadIdx.x, lane = tid & 63, w = tid >> 6;  // 8 waves
    const int wr = w >> 2, wc = w & 3;       // wave grid 2(M) x 4(N)
    const int col = lane & 15, quad = lane >> 4;

    // XCD-bijective swizzle (nwg % 8 == 0), then decompose into (bm, bn).
    const int nwg = gridDim.x, cpx = nwg >> 3;
    const int swz = ((int)blockIdx.x & 7) * cpx + ((int)blockIdx.x >> 3);
    const long m0 = (long)(swz >> 3) * 256;
    const long n0 = (long)(swz & 7) * 256;

    // per-lane global bases for fragment-permuted staging:
    // stage block blk (0..31): g=blk>>1 (16-row group), kk=blk&1 (32-k chunk);
    // lane l supplies [g*16 + (l&15)][kk*32 + (l>>4)*8 ..+8].
    const uint16_t* Ab = A + (m0 + col) * (size_t)DMODEL + quad * 8;
    const uint16_t* Bb = Bt + (n0 + col) * (size_t)DMODEL + quad * 8;

#define STAGE256(bf, kt)                                                       \
    {                                                                          \
        const size_t kb = (size_t)(kt) * 64;                                   \
        _Pragma("unroll") for (int j = 0; j < 4; j++) {                        \
            const int blk = w * 4 + j;                                         \
            const size_t off =                                                 \
                kb + (size_t)(blk >> 1) * (16 * DMODEL) + (size_t)(blk & 1) * 32; \
            GLD16(Ab + off, &As[bf][blk * 512]);                               \
            GLD16(Bb + off, &Bs[bf][blk * 512]);                               \
        }                                                                      \
    }

    floatx4 acc[8][4];
#pragma unroll
    for (int m = 0; m < 8; m++)
#pragma unroll
        for (int n = 0; n < 4; n++) acc[m][n] = (floatx4){0.f, 0.f, 0.f, 0.f};

    const int NT = DMODEL / 64;  // 32 K-tiles
    STAGE256(0, 0);
    STAGE256(1, 1);

#pragma unroll 1
    for (int kt = 0; kt < NT; ++kt) {
        const int cur = kt & 1;
        // retire the loads for tile kt (issued 2 iterations ago); the 8 loads
        // for tile kt+1 stay in flight across this whole iteration.
        if (kt == NT - 1) { WAITVMC(0); } else { WAITVMC(8); }
        __builtin_amdgcn_s_barrier();

        bf16x8 a0[8], b0[4];
#pragma unroll
        for (int m = 0; m < 8; m++)
            a0[m] = *(const bf16x8*)&As[cur][((wr * 8 + m) * 2 + 0) * 512 + lane * 8];
#pragma unroll
        for (int n = 0; n < 4; n++)
            b0[n] = *(const bf16x8*)&Bs[cur][((wc * 4 + n) * 2 + 0) * 512 + lane * 8];
        // kk0 MFMA can start while kk1 reads issue (same region, no barrier)
        __builtin_amdgcn_s_setprio(1);
#pragma unroll
        for (int m = 0; m < 8; m++)
#pragma unroll
            for (int n = 0; n < 4; n++)
                acc[m][n] = __builtin_amdgcn_mfma_f32_16x16x32_bf16(a0[m], b0[n],
                                                                    acc[m][n], 0, 0, 0);
        __builtin_amdgcn_s_setprio(0);

        bf16x8 a1[8], b1[4];
#pragma unroll
        for (int m = 0; m < 8; m++)
            a1[m] = *(const bf16x8*)&As[cur][((wr * 8 + m) * 2 + 1) * 512 + lane * 8];
#pragma unroll
        for (int n = 0; n < 4; n++)
            b1[n] = *(const bf16x8*)&Bs[cur][((wc * 4 + n) * 2 + 1) * 512 + lane * 8];
        WAITLGKM0;                       // all reads of buf[cur] complete
        __builtin_amdgcn_s_barrier();    // ... in every wave -> buffer free
        if (kt + 2 < NT) STAGE256(cur, kt + 2);  // overlaps with MFMA below
        __builtin_amdgcn_s_setprio(1);
#pragma unroll
        for (int m = 0; m < 8; m++)
#pragma unroll
            for (int n = 0; n < 4; n++)
                acc[m][n] = __builtin_amdgcn_mfma_f32_16x16x32_bf16(a1[m], b1[n],
                                                                    acc[m][n], 0, 0, 0);
        __builtin_amdgcn_s_setprio(0);
    }

    // epilogue
    float bv[4];
#pragma unroll
    for (int n = 0; n < 4; n++) bv[n] = bias[n0 + wc * 64 + n * 16 + col];
#pragma unroll
    for (int m = 0; m < 8; m++) {
        const long row = m0 + wr * 128 + m * 16 + quad * 4;
#pragma unroll
        for (int n = 0; n < 4; n++) {
            const long cc = n0 + wc * 64 + n * 16 + col;
            if (mode == 2) {
                uint16_t tmp[4] __attribute__((aligned(8)));
#pragma unroll
                for (int r = 0; r < 4; r++)
                    tmp[r] = f2b((acc[m][n][r] + bv[n]) * scale);
                *(uint2*)&((uint16_t*)Cout)[(size_t)cc * tld + row] =
                    *(const uint2*)tmp;
            } else {
#pragma unroll
                for (int r = 0; r < 4; r++) {
                    const float v = (acc[m][n][r] + bv[n]) * scale;
                    const long idx = (row + r) * DMODEL + cc;
                    if (mode == 1) ((float*)Cout)[idx] = v;
                    else           ((uint16_t*)Cout)[idx] = f2b(v);
                }
            }
        }
    }
#undef STAGE256
}

// ---------------------------------------------------------------------------
// 128-tile GEMM (m97 structure) — kept for the per-batch fallback paths.
// ---------------------------------------------------------------------------
__global__ __launch_bounds__(256, 2) void gemm(const uint16_t* __restrict__ A,
                                               const uint16_t* __restrict__ Bt,
                                               const float* __restrict__ bias,
                                               void* __restrict__ Cout,
                                               float scale, int mode, int tld) {
    __shared__ __attribute__((aligned(16))) uint16_t As[128 * 32];
    __shared__ __attribute__((aligned(16))) uint16_t Bs[128 * 32];
    const int tid = threadIdx.x, lane = tid & 63, w = tid >> 6;
    const int wr = w >> 1, wc = w & 1;
    const int col = lane & 15, quad = lane >> 4;
    const long m0 = (long)blockIdx.y * 128, n0 = (long)blockIdx.x * 128;

    floatx4 acc[4][4];
#pragma unroll
    for (int i = 0; i < 4; i++)
#pragma unroll
        for (int j = 0; j < 4; j++) acc[i][j] = (floatx4){0.f, 0.f, 0.f, 0.f};

    const int srow = tid >> 2, sc = (tid & 3) << 3;
    const uint16_t* Ag0 = A + (m0 + srow) * DMODEL + sc;
    const uint16_t* Bg0 = Bt + (n0 + srow) * DMODEL + sc;
    const long rstep = (long)64 * DMODEL;
    uint16_t* AsW = &As[w * 512];
    uint16_t* BsW = &Bs[w * 512];

    for (int kt = 0; kt < DMODEL; kt += 32) {
        GLD16(Ag0 + kt, AsW);
        GLD16(Ag0 + rstep + kt, AsW + 2048);
        GLD16(Bg0 + kt, BsW);
        GLD16(Bg0 + rstep + kt, BsW + 2048);
        __syncthreads();
        bf16x8 af[4], bfr[4];
#pragma unroll
        for (int i = 0; i < 4; i++)
            af[i] = *(const bf16x8*)&As[(wr * 64 + i * 16 + col) * 32 + quad * 8];
#pragma unroll
        for (int j = 0; j < 4; j++)
            bfr[j] = *(const bf16x8*)&Bs[(wc * 64 + j * 16 + col) * 32 + quad * 8];
#pragma unroll
        for (int i = 0; i < 4; i++)
#pragma unroll
            for (int j = 0; j < 4; j++)
                acc[i][j] = __builtin_amdgcn_mfma_f32_16x16x32_bf16(af[i], bfr[j],
                                                                    acc[i][j], 0, 0, 0);
        __syncthreads();
    }

    float bv[4];
#pragma unroll
    for (int j = 0; j < 4; j++) bv[j] = bias[n0 + wc * 64 + j * 16 + col];
#pragma unroll
    for (int i = 0; i < 4; i++) {
        const long row = m0 + wr * 64 + i * 16 + quad * 4;
#pragma unroll
        for (int j = 0; j < 4; j++) {
            const long cc = n0 + wc * 64 + j * 16 + col;
            if (mode == 2) {
                uint16_t tmp[4] __attribute__((aligned(8)));
#pragma unroll
                for (int r = 0; r < 4; r++)
                    tmp[r] = f2b((acc[i][j][r] + bv[j]) * scale);
                *(uint2*)&((uint16_t*)Cout)[(size_t)cc * tld + row] =
                    *(const uint2*)tmp;
            } else {
#pragma unroll
                for (int r = 0; r < 4; r++) {
                    const float v = (acc[i][j][r] + bv[j]) * scale;
                    const long idx = (row + r) * DMODEL + cc;
                    if (mode == 1) ((float*)Cout)[idx] = v;
                    else           ((uint16_t*)Cout)[idx] = f2b(v);
                }
            }
        }
    }
}

// ---------------------------------------------------------------------------
// Flash attention, causal, in-place (O overwrites Q). Q/K bf16 [rows x 2048],
// head h at cols h*128, batch b at rows b*2048. Q pre-scaled by 1/sqrt(HD).
// V comes in TRANSPOSED: Vt bf16 [2048 n][vld m], n = h*128+d, m = b*SEQ+t.
// K and V stored FRAGMENT-LINEAR in LDS (conflict-free writes+reads).
// Causal load balance: block x handles q-tiles (15-x) then (x) -> every block
// does exactly 34 K-tiles. grid (8, nbatch*16) = 512 blocks = 2/CU, no tail.
// (unchanged this round)
// ---------------------------------------------------------------------------
__global__ __launch_bounds__(256, 2) void flash(uint16_t* __restrict__ QO,
                                                const uint16_t* __restrict__ Kp,
                                                const uint16_t* __restrict__ Vt,
                                                int vld) {
    __shared__ __attribute__((aligned(16))) uint16_t Ks[16 * 512];
    __shared__ __attribute__((aligned(16))) uint16_t Vs[16 * 512];
    __shared__ __attribute__((aligned(16))) uint16_t Ps[4][32 * 88];

    const int tid = threadIdx.x, lane = tid & 63, w = tid >> 6;
    const int col = lane & 15, quad = lane >> 4;
    const int h = blockIdx.y & 15, b = blockIdx.y >> 4;
    const size_t brow = (size_t)b * SEQ;

    const uint16_t* kbase = Kp + brow * DMODEL + h * HD;
    const uint16_t* vtbase = Vt + (size_t)(h * HD) * vld + brow;
    const uint16_t* kg0 = kbase + (size_t)(w * 16 + col) * DMODEL + quad * 8;
    const uint16_t* vg0 = vtbase + (size_t)(w * 32 + col) * vld + quad * 8;

    for (int half = 0; half < 2; ++half) {
        const int qi = half ? (int)blockIdx.x : (15 - (int)blockIdx.x);
        const int q0 = qi * 128;
        uint16_t* qbase = QO + (brow + q0 + w * 32) * DMODEL + h * HD;

        bf16x8 qf[2][4];
#pragma unroll
        for (int i = 0; i < 2; i++)
#pragma unroll
            for (int kk = 0; kk < 4; kk++)
                qf[i][kk] = *(const bf16x8*)(qbase + (size_t)(i * 16 + col) * DMODEL +
                                             kk * 32 + quad * 8);

        floatx4 accO[2][8];
#pragma unroll
        for (int i = 0; i < 2; i++)
#pragma unroll
            for (int jd = 0; jd < 8; jd++) accO[i][jd] = (floatx4){0.f, 0.f, 0.f, 0.f};
        float mrun[2][4], lrun[2][4];
#pragma unroll
        for (int i = 0; i < 2; i++)
#pragma unroll
            for (int r = 0; r < 4; r++) { mrun[i][r] = -1e30f; lrun[i][r] = 0.f; }

        const int nkt = 2 * qi + 2;

        uint4 kv[4], vv4[4];
        {
#pragma unroll
            for (int p = 0; p < 4; p++)
                kv[p] = *(const uint4*)(kg0 + p * 32);
#pragma unroll
            for (int s = 0; s < 2; s++)
#pragma unroll
                for (int k2 = 0; k2 < 2; k2++)
                    vv4[s * 2 + k2] =
                        *(const uint4*)(vg0 + (size_t)s * 16 * vld + k2 * 32);
        }

        for (int ki = 0; ki < nkt; ki++) {
            const int key0 = ki * 64;
#pragma unroll
            for (int p = 0; p < 4; p++)
                *(uint4*)&Ks[(w * 4 + p) * 512 + lane * 8] = kv[p];
#pragma unroll
            for (int s = 0; s < 2; s++)
#pragma unroll
                for (int k2 = 0; k2 < 2; k2++)
                    *(uint4*)&Vs[((w * 2 + s) * 2 + k2) * 512 + lane * 8] =
                        vv4[s * 2 + k2];
            __syncthreads();

            if (ki + 1 < nkt) {
                const size_t koff = (size_t)(key0 + 64);
#pragma unroll
                for (int p = 0; p < 4; p++)
                    kv[p] = *(const uint4*)(kg0 + koff * DMODEL + p * 32);
#pragma unroll
                for (int s = 0; s < 2; s++)
#pragma unroll
                    for (int k2 = 0; k2 < 2; k2++)
                        vv4[s * 2 + k2] = *(const uint4*)(vg0 + (size_t)s * 16 * vld +
                                                          koff + k2 * 32);
            }

            floatx4 s[2][4];
            __builtin_amdgcn_s_setprio(1);
#pragma unroll
            for (int i = 0; i < 2; i++)
#pragma unroll
                for (int jk = 0; jk < 4; jk++) {
                    floatx4 a = (floatx4){0.f, 0.f, 0.f, 0.f};
#pragma unroll
                    for (int kk = 0; kk < 4; kk++) {
                        bf16x8 bb = *(const bf16x8*)&Ks[(jk * 4 + kk) * 512 + lane * 8];
                        a = __builtin_amdgcn_mfma_f32_16x16x32_bf16(qf[i][kk], bb, a, 0, 0, 0);
                    }
                    s[i][jk] = a;
                }
            __builtin_amdgcn_s_setprio(0);

            if (key0 + 63 > q0 + w * 32) {
#pragma unroll
                for (int i = 0; i < 2; i++) {
                    const int qb = q0 + w * 32 + i * 16 + quad * 4;
#pragma unroll
                    for (int jk = 0; jk < 4; jk++) {
                        const int key = key0 + jk * 16 + col;
#pragma unroll
                        for (int r = 0; r < 4; r++)
                            if (key > qb + r) s[i][jk][r] = -1e30f;
                    }
                }
            }

            float alpha[2][4];
#pragma unroll
            for (int i = 0; i < 2; i++)
#pragma unroll
                for (int r = 0; r < 4; r++) {
                    float mx = s[i][0][r];
#pragma unroll
                    for (int jk = 1; jk < 4; jk++) mx = fmaxf(mx, s[i][jk][r]);
                    mx = fmaxf(mx, __shfl_xor(mx, 1, 64));
                    mx = fmaxf(mx, __shfl_xor(mx, 2, 64));
                    mx = fmaxf(mx, __shfl_xor(mx, 4, 64));
                    mx = fmaxf(mx, __shfl_xor(mx, 8, 64));
                    mx = fmaxf(mx, mrun[i][r]);
                    alpha[i][r] = exp2f((mrun[i][r] - mx) * LOG2E);
                    mrun[i][r] = mx;
                }
#pragma unroll
            for (int i = 0; i < 2; i++)
#pragma unroll
                for (int r = 0; r < 4; r++) {
                    float psum = 0.f;
#pragma unroll
                    for (int jk = 0; jk < 4; jk++) {
                        const float p = exp2f((s[i][jk][r] - mrun[i][r]) * LOG2E);
                        psum += p;
                        Ps[w][(i * 16 + quad * 4 + r) * 88 + jk * 16 + col] = f2b(p);
                    }
                    lrun[i][r] = lrun[i][r] * alpha[i][r] + psum;
                }
#pragma unroll
            for (int i = 0; i < 2; i++)
#pragma unroll
                for (int jd = 0; jd < 8; jd++)
#pragma unroll
                    for (int r = 0; r < 4; r++) accO[i][jd][r] *= alpha[i][r];

            bf16x8 pf[2][2];
#pragma unroll
            for (int i = 0; i < 2; i++)
#pragma unroll
                for (int k2 = 0; k2 < 2; k2++)
                    pf[i][k2] = *(const bf16x8*)&Ps[w][(i * 16 + col) * 88 + k2 * 32 + quad * 8];
            __builtin_amdgcn_s_setprio(1);
#pragma unroll
            for (int jd = 0; jd < 8; jd++)
#pragma unroll
                for (int k2 = 0; k2 < 2; k2++) {
                    bf16x8 vvv = *(const bf16x8*)&Vs[(jd * 2 + k2) * 512 + lane * 8];
#pragma unroll
                    for (int i = 0; i < 2; i++)
                        accO[i][jd] = __builtin_amdgcn_mfma_f32_16x16x32_bf16(pf[i][k2], vvv,
                                                                              accO[i][jd], 0, 0, 0);
                }
            __builtin_amdgcn_s_setprio(0);
            __syncthreads();
        }

        float inv[2][4];
#pragma unroll
        for (int i = 0; i < 2; i++)
#pragma unroll
            for (int r = 0; r < 4; r++) {
                float l = lrun[i][r];
                l += __shfl_xor(l, 1, 64);
                l += __shfl_xor(l, 2, 64);
                l += __shfl_xor(l, 4, 64);
                l += __shfl_xor(l, 8, 64);
                inv[i][r] = 1.0f / l;
            }
#pragma unroll
        for (int i = 0; i < 2; i++)
#pragma unroll
            for (int jd = 0; jd < 8; jd++)
#pragma unroll
                for (int r = 0; r < 4; r++)
                    qbase[(size_t)(i * 16 + quad * 4 + r) * DMODEL + jd * 16 + col] =
                        f2b(accO[i][jd][r] * inv[i][r]);
    }
}

// ---------------------------------------------------------------------------
extern "C" void kernel_launch(void* const* d_in, const int* in_sizes, int n_in,
                              void* d_out, int out_size, void* d_ws, size_t ws_size,
                              hipStream_t stream) {
    const float* X   = (const float*)d_in[0];
    float*       msk = (float*)d_in[1];  // scratch in tiny-ws fallback
    const float* wq  = (const float*)d_in[2];
    const float* wqb = (const float*)d_in[3];
    const float* wk  = (const float*)d_in[4];
    const float* wkb = (const float*)d_in[5];
    const float* wv  = (const float*)d_in[6];
    const float* wvb = (const float*)d_in[7];
    const float* wo  = (const float*)d_in[8];
    const float* wob = (const float*)d_in[9];
    float* out = (float*)d_out;

    char* ws = (char*)d_ws;
    const size_t MB = 1ull << 20;
    dim3 tb(256), tb512(512), gT(32, 32);
    const float qs = 0.08838834764831845f;  // 1/sqrt(128)

    if (ws_size >= 136 * MB) {
        // ---- whole-problem path ----
        uint16_t* Xb = (uint16_t*)(ws);
        uint16_t* Qb = (uint16_t*)(ws + 32 * MB);
        uint16_t* Kb = (uint16_t*)(ws + 64 * MB);
        uint16_t* Vb = (uint16_t*)(ws + 96 * MB);  // holds Vt [2048][8192]
        uint16_t* Wt = (uint16_t*)(ws + 128 * MB);
        dim3 g256((MTOT / 256) * (DMODEL / 256));  // 256 blocks, 1/CU
        dim3 gF(8, 64);
        cvt_bf16<<<8192, tb, 0, stream>>>(X, Xb, MTOT * DMODEL);
        tr_wf<<<gT, tb, 0, stream>>>(wq, Wt);
        gemm256<<<g256, tb512, 0, stream>>>(Xb, Wt, wqb, Qb, qs, 0, 0);
        tr_wf<<<gT, tb, 0, stream>>>(wk, Wt);
        gemm256<<<g256, tb512, 0, stream>>>(Xb, Wt, wkb, Kb, 1.0f, 0, 0);
        tr_wf<<<gT, tb, 0, stream>>>(wv, Wt);
        gemm256<<<g256, tb512, 0, stream>>>(Xb, Wt, wvb, Vb, 1.0f, 2, MTOT);
        flash<<<gF, tb, 0, stream>>>(Qb, Kb, Vb, MTOT);  // ctx in-place over Q
        tr_wf<<<gT, tb, 0, stream>>>(wo, Wt);
        gemm256<<<g256, tb512, 0, stream>>>(Qb, Wt, wob, out, 1.0f, 1, 0);
    } else {
        // ---- per-batch paths (128-tile gemm kept here) ----
        uint16_t* Xb = (uint16_t*)(ws);
        uint16_t* Qb = (uint16_t*)(ws + 8 * MB);
        uint16_t *Kb, *Vb, *Wt;
        if (ws_size >= 40 * MB) {
            Kb = (uint16_t*)(ws + 16 * MB);
            Vb = (uint16_t*)(ws + 24 * MB);
            Wt = (uint16_t*)(ws + 32 * MB);
        } else {
            Kb = (uint16_t*)msk;
            Vb = Kb + (size_t)SEQ * DMODEL;
            Wt = (uint16_t*)(ws + 16 * MB);
        }
        dim3 gG(16, 16), gF(8, 16);
        for (int b = 0; b < BATCH; b++) {
            const float* Xf = X + (size_t)b * SEQ * DMODEL;
            float* Ob = out + (size_t)b * SEQ * DMODEL;
            cvt_bf16<<<2048, tb, 0, stream>>>(Xf, Xb, SEQ * DMODEL);
            tr_wf<<<gT, tb, 0, stream>>>(wq, Wt);
            gemm<<<gG, tb, 0, stream>>>(Xb, Wt, wqb, Qb, qs, 0, 0);
            tr_wf<<<gT, tb, 0, stream>>>(wk, Wt);
            gemm<<<gG, tb, 0, stream>>>(Xb, Wt, wkb, Kb, 1.0f, 0, 0);
            tr_wf<<<gT, tb, 0, stream>>>(wv, Wt);
            gemm<<<gG, tb, 0, stream>>>(Xb, Wt, wvb, Vb, 1.0f, 2, SEQ);
            flash<<<gF, tb, 0, stream>>>(Qb, Kb, Vb, SEQ);
            tr_wf<<<gT, tb, 0, stream>>>(wo, Wt);
            gemm<<<gG, tb, 0, stream>>>(Qb, Wt, wob, Ob, 1.0f, 1, 0);
        }
    }

    (void)in_sizes; (void)n_in; (void)out_size;
}

// Round 8
// 714.193 us; speedup vs baseline: 1.0538x; 1.0538x over previous
//
#include <hip/hip_runtime.h>
#include <stdint.h>

#define DMODEL 2048
#define NH 16
#define HD 128
#define BATCH 4
#define SEQ 2048
#define MTOT (BATCH * SEQ)  // 8192
#define LOG2E 1.44269504088896340736f

typedef __bf16 bf16x8 __attribute__((ext_vector_type(8)));
typedef float floatx4 __attribute__((ext_vector_type(4)));

__device__ __forceinline__ uint16_t f2b(float f) {
    union { float f; uint32_t i; } v; v.f = f;
    uint32_t r = v.i + 0x7fffu + ((v.i >> 16) & 1u);
    return (uint16_t)(r >> 16);
}

// async global->LDS, 16B per lane, wave-uniform LDS base + lane*16
#define GLD16(gp, lp)                                                          \
    __builtin_amdgcn_global_load_lds(                                          \
        (__attribute__((address_space(1))) unsigned int*)(gp),                 \
        (__attribute__((address_space(3))) unsigned int*)(lp), 16, 0, 0)

#define WAITVMC(N) asm volatile("s_waitcnt vmcnt(" #N ")" ::: "memory")
#define WAITLGKM0                                                              \
    do {                                                                       \
        asm volatile("s_waitcnt lgkmcnt(0)" ::: "memory");                     \
        __builtin_amdgcn_sched_barrier(0);                                     \
    } while (0)

// ---------------------------------------------------------------------------
// fp32 -> bf16 elementwise convert. n multiple of 8. grid n/2048.
// ---------------------------------------------------------------------------
__global__ __launch_bounds__(256) void cvt_bf16(const float* __restrict__ in,
                                                uint16_t* __restrict__ out, int n) {
    const int i = (blockIdx.x * 256 + threadIdx.x) * 8;
    if (i >= n) return;
    const float4 a = *(const float4*)(in + i);
    const float4 b = *(const float4*)(in + i + 4);
    uint16_t v[8] __attribute__((aligned(16))) = {
        f2b(a.x), f2b(a.y), f2b(a.z), f2b(a.w),
        f2b(b.x), f2b(b.y), f2b(b.z), f2b(b.w)};
    *(uint4*)(out + i) = *(const uint4*)v;
}

// ---------------------------------------------------------------------------
// Weight transpose+convert: W fp32 [k][n] (2048x2048) -> Wt bf16 [n][k].
// grid (32,32), 64x64 tiles.
// ---------------------------------------------------------------------------
__global__ __launch_bounds__(256) void tr_wf(const float* __restrict__ in,
                                             uint16_t* __restrict__ out) {
    __shared__ float t[64 * 69];  // stride 69: 2-way max bank aliasing (free)
    const int tid = threadIdx.x;
    const int r0 = blockIdx.y * 64, c0 = blockIdx.x * 64;
    const int rr = tid >> 2, c16 = (tid & 3) << 4;
#pragma unroll
    for (int j = 0; j < 4; j++)
        *(float4*)&t[rr * 69 + c16 + j * 4] =
            *(const float4*)(in + (size_t)(r0 + rr) * DMODEL + c0 + c16 + j * 4);
    __syncthreads();
    const int oc = tid >> 2, r16 = (tid & 3) << 4;
    uint16_t v[16] __attribute__((aligned(16)));
#pragma unroll
    for (int j = 0; j < 16; j++) v[j] = f2b(t[(r16 + j) * 69 + oc]);
    uint16_t* o = out + (size_t)(c0 + oc) * DMODEL + r0 + r16;
    *(uint4*)o = *(const uint4*)v;
    *(uint4*)(o + 8) = *(const uint4*)(v + 8);
}

// ---------------------------------------------------------------------------
// 256x256 GEMM, BK=64, 8 waves (512 thr), PER-PHASE 8-phase-style schedule
// (T3+T4+T5; m196/m201: the fine interleave is the lever, coarse split is
// not). 4 phases per K-tile = (m-half x kk). Each phase:
//   {4-8 ds_read_b128} {2 global_load_lds half-stage} barrier
//   lgkmcnt(0)+sched_barrier  setprio(1) 16 MFMA setprio(0)  [vmcnt] barrier
// Counted vmcnt: vmcnt(8) at phases 1,3 only (never 0 in steady state);
// tail peels to vmcnt(2) at tile NT-2 / vmcnt(0) at tile NT-1.
// Half-tile = (operand, kk) = 16 blocks of 1KiB; staged 2 GLD/thread; its
// last reader phase is 2 barriers before its stage phase (write-safe).
// LDS is FRAGMENT-LINEAR (block = MFMA fragment, slot = lane): both
// global_load_lds (linear dest) and ds_read_b128 (contiguous 1KiB) are
// conflict-free; fragment permutation lives in the per-lane global source.
// grid = (M/256)*8 blocks 1-D, XCD-bijective swizzle. 1 block/CU (128KiB).
// mode 0: C bf16 [m][n]; 1: C fp32; 2: C bf16 transposed [n][m] ld=tld.
// ---------------------------------------------------------------------------
__global__ __launch_bounds__(512, 2) void gemm256(const uint16_t* __restrict__ A,
                                                  const uint16_t* __restrict__ Bt,
                                                  const float* __restrict__ bias,
                                                  void* __restrict__ Cout,
                                                  float scale, int mode, int tld) {
    __shared__ __attribute__((aligned(16))) uint16_t As[2][32 * 512];  // 2x32KiB
    __shared__ __attribute__((aligned(16))) uint16_t Bs[2][32 * 512];  // 2x32KiB

    const int tid = threadIdx.x, lane = tid & 63, w = tid >> 6;  // 8 waves
    const int wr = w >> 2, wc = w & 3;       // wave grid 2(M) x 4(N)
    const int col = lane & 15, quad = lane >> 4;

    // XCD-bijective swizzle (nwg % 8 == 0), then decompose into (bm, bn).
    const int nwg = gridDim.x, cpx = nwg >> 3;
    const int swz = ((int)blockIdx.x & 7) * cpx + ((int)blockIdx.x >> 3);
    const long m0 = (long)(swz >> 3) * 256;
    const long n0 = (long)(swz & 7) * 256;

    // per-lane global bases: block (g,kk) lane l holds
    // [g*16 + (l&15)][kt*64 + kk*32 + (l>>4)*8 ..+8]
    const uint16_t* Ab = A + (m0 + col) * (size_t)DMODEL + quad * 8;
    const uint16_t* Bb = Bt + (n0 + col) * (size_t)DMODEL + quad * 8;
    const int g0 = w * 2, g1 = w * 2 + 1;  // this wave's stage row-groups

#define STG_A(bf, kt, kk)                                                      \
    do {                                                                       \
        GLD16(Ab + (size_t)(g0 * 16) * DMODEL + (kt) * 64 + (kk) * 32,         \
              &As[bf][(g0 * 2 + (kk)) * 512]);                                 \
        GLD16(Ab + (size_t)(g1 * 16) * DMODEL + (kt) * 64 + (kk) * 32,         \
              &As[bf][(g1 * 2 + (kk)) * 512]);                                 \
    } while (0)
#define STG_B(bf, kt, kk)                                                      \
    do {                                                                       \
        GLD16(Bb + (size_t)(g0 * 16) * DMODEL + (kt) * 64 + (kk) * 32,         \
              &Bs[bf][(g0 * 2 + (kk)) * 512]);                                 \
        GLD16(Bb + (size_t)(g1 * 16) * DMODEL + (kt) * 64 + (kk) * 32,         \
              &Bs[bf][(g1 * 2 + (kk)) * 512]);                                 \
    } while (0)

    floatx4 acc[8][4];
#pragma unroll
    for (int m = 0; m < 8; m++)
#pragma unroll
        for (int n = 0; n < 4; n++) acc[m][n] = (floatx4){0.f, 0.f, 0.f, 0.f};

    const int NT = DMODEL / 64;  // 32 K-tiles
    // prologue: issue order must match steady-state retire accounting.
    STG_A(0, 0, 0); STG_B(0, 0, 0);
    STG_A(0, 0, 1); STG_B(0, 0, 1);
    STG_A(1, 1, 0); STG_B(1, 1, 0);    // 12 loads in flight
    WAITVMC(8);                        // retire A0(0),B0(0)
    __builtin_amdgcn_s_barrier();

    bf16x8 afr[4], bfr[4];

// phase: m-half MS, k-chunk KK; READB: load b-frags (first use of KK).
#define PHASE(MS, KK, READB, STAGE_STMT, TAILW)                                \
    do {                                                                       \
        if (READB) {                                                           \
            _Pragma("unroll") for (int n = 0; n < 4; n++)                      \
                bfr[n] = *(const bf16x8*)&Bs[cur][((wc * 4 + n) * 2 + (KK)) *  \
                                                     512 + lane * 8];          \
        }                                                                      \
        _Pragma("unroll") for (int m = 0; m < 4; m++)                          \
            afr[m] = *(const bf16x8*)&As[cur][((wr * 8 + (MS)*4 + m) * 2 +     \
                                               (KK)) * 512 + lane * 8];        \
        STAGE_STMT;                                                            \
        __builtin_amdgcn_s_barrier();                                          \
        WAITLGKM0;                                                             \
        __builtin_amdgcn_s_setprio(1);                                         \
        _Pragma("unroll") for (int m = 0; m < 4; m++)                          \
            _Pragma("unroll") for (int n = 0; n < 4; n++)                      \
                acc[(MS)*4 + m][n] = __builtin_amdgcn_mfma_f32_16x16x32_bf16(  \
                    afr[m], bfr[n], acc[(MS)*4 + m][n], 0, 0, 0);              \
        __builtin_amdgcn_s_setprio(0);                                         \
        TAILW;                                                                 \
        __builtin_amdgcn_s_barrier();                                          \
    } while (0)

#pragma unroll 1
    for (int t = 0; t < NT; ++t) {
        const int cur = t & 1, nxt = cur ^ 1;
        // P0: (ms0,kk0); stage A-kk1(t+1) -> nxt (its blocks were read at
        //     t-1's P2/P3; two barriers ago -> safe)
        PHASE(0, 0, 1, { if (t + 1 < NT) STG_A(nxt, t + 1, 1); }, {});
        // P1: (ms1,kk0); stage B-kk1(t+1); vmcnt retires A1(t),B1(t) for P2
        PHASE(1, 0, 0, { if (t + 1 < NT) STG_B(nxt, t + 1, 1); },
              { if (t == NT - 1) { WAITVMC(0); } else { WAITVMC(8); } });
        // P2: (ms0,kk1); stage A-kk0(t+2) -> cur (kk0 blocks read at P0/P1)
        PHASE(0, 1, 1, { if (t + 2 < NT) STG_A(cur, t + 2, 0); }, {});
        // P3: (ms1,kk1); stage B-kk0(t+2); vmcnt retires A0(t+1),B0(t+1)
        PHASE(1, 1, 0, { if (t + 2 < NT) STG_B(cur, t + 2, 0); },
              { if (t == NT - 2) { WAITVMC(2); }
                else if (t < NT - 2) { WAITVMC(8); } });
    }
#undef PHASE
#undef STG_A
#undef STG_B

    // epilogue
    float bv[4];
#pragma unroll
    for (int n = 0; n < 4; n++) bv[n] = bias[n0 + wc * 64 + n * 16 + col];
#pragma unroll
    for (int m = 0; m < 8; m++) {
        const long row = m0 + wr * 128 + m * 16 + quad * 4;
#pragma unroll
        for (int n = 0; n < 4; n++) {
            const long cc = n0 + wc * 64 + n * 16 + col;
            if (mode == 2) {
                uint16_t tmp[4] __attribute__((aligned(8)));
#pragma unroll
                for (int r = 0; r < 4; r++)
                    tmp[r] = f2b((acc[m][n][r] + bv[n]) * scale);
                *(uint2*)&((uint16_t*)Cout)[(size_t)cc * tld + row] =
                    *(const uint2*)tmp;
            } else {
#pragma unroll
                for (int r = 0; r < 4; r++) {
                    const float v = (acc[m][n][r] + bv[n]) * scale;
                    const long idx = (row + r) * DMODEL + cc;
                    if (mode == 1) ((float*)Cout)[idx] = v;
                    else           ((uint16_t*)Cout)[idx] = f2b(v);
                }
            }
        }
    }
}

// ---------------------------------------------------------------------------
// 128-tile GEMM (m97 structure) — kept for the per-batch fallback paths.
// ---------------------------------------------------------------------------
__global__ __launch_bounds__(256, 2) void gemm(const uint16_t* __restrict__ A,
                                               const uint16_t* __restrict__ Bt,
                                               const float* __restrict__ bias,
                                               void* __restrict__ Cout,
                                               float scale, int mode, int tld) {
    __shared__ __attribute__((aligned(16))) uint16_t As[128 * 32];
    __shared__ __attribute__((aligned(16))) uint16_t Bs[128 * 32];
    const int tid = threadIdx.x, lane = tid & 63, w = tid >> 6;
    const int wr = w >> 1, wc = w & 1;
    const int col = lane & 15, quad = lane >> 4;
    const long m0 = (long)blockIdx.y * 128, n0 = (long)blockIdx.x * 128;

    floatx4 acc[4][4];
#pragma unroll
    for (int i = 0; i < 4; i++)
#pragma unroll
        for (int j = 0; j < 4; j++) acc[i][j] = (floatx4){0.f, 0.f, 0.f, 0.f};

    const int srow = tid >> 2, sc = (tid & 3) << 3;
    const uint16_t* Ag0 = A + (m0 + srow) * DMODEL + sc;
    const uint16_t* Bg0 = Bt + (n0 + srow) * DMODEL + sc;
    const long rstep = (long)64 * DMODEL;
    uint16_t* AsW = &As[w * 512];
    uint16_t* BsW = &Bs[w * 512];

    for (int kt = 0; kt < DMODEL; kt += 32) {
        GLD16(Ag0 + kt, AsW);
        GLD16(Ag0 + rstep + kt, AsW + 2048);
        GLD16(Bg0 + kt, BsW);
        GLD16(Bg0 + rstep + kt, BsW + 2048);
        __syncthreads();
        bf16x8 af[4], bfr[4];
#pragma unroll
        for (int i = 0; i < 4; i++)
            af[i] = *(const bf16x8*)&As[(wr * 64 + i * 16 + col) * 32 + quad * 8];
#pragma unroll
        for (int j = 0; j < 4; j++)
            bfr[j] = *(const bf16x8*)&Bs[(wc * 64 + j * 16 + col) * 32 + quad * 8];
#pragma unroll
        for (int i = 0; i < 4; i++)
#pragma unroll
            for (int j = 0; j < 4; j++)
                acc[i][j] = __builtin_amdgcn_mfma_f32_16x16x32_bf16(af[i], bfr[j],
                                                                    acc[i][j], 0, 0, 0);
        __syncthreads();
    }

    float bv[4];
#pragma unroll
    for (int j = 0; j < 4; j++) bv[j] = bias[n0 + wc * 64 + j * 16 + col];
#pragma unroll
    for (int i = 0; i < 4; i++) {
        const long row = m0 + wr * 64 + i * 16 + quad * 4;
#pragma unroll
        for (int j = 0; j < 4; j++) {
            const long cc = n0 + wc * 64 + j * 16 + col;
            if (mode == 2) {
                uint16_t tmp[4] __attribute__((aligned(8)));
#pragma unroll
                for (int r = 0; r < 4; r++)
                    tmp[r] = f2b((acc[i][j][r] + bv[j]) * scale);
                *(uint2*)&((uint16_t*)Cout)[(size_t)cc * tld + row] =
                    *(const uint2*)tmp;
            } else {
#pragma unroll
                for (int r = 0; r < 4; r++) {
                    const float v = (acc[i][j][r] + bv[j]) * scale;
                    const long idx = (row + r) * DMODEL + cc;
                    if (mode == 1) ((float*)Cout)[idx] = v;
                    else           ((uint16_t*)Cout)[idx] = f2b(v);
                }
            }
        }
    }
}

// ---------------------------------------------------------------------------
// Flash attention, causal, in-place (O overwrites Q). Q/K bf16 [rows x 2048],
// head h at cols h*128, batch b at rows b*2048. Q pre-scaled by 1/sqrt(HD).
// V comes in TRANSPOSED: Vt bf16 [2048 n][vld m], n = h*128+d, m = b*SEQ+t.
// K and V stored FRAGMENT-LINEAR in LDS (conflict-free writes+reads).
// Causal load balance: block x handles q-tiles (15-x) then (x) -> every block
// does exactly 34 K-tiles. grid (8, nbatch*16) = 512 blocks = 2/CU, no tail.
// (unchanged this round)
// ---------------------------------------------------------------------------
__global__ __launch_bounds__(256, 2) void flash(uint16_t* __restrict__ QO,
                                                const uint16_t* __restrict__ Kp,
                                                const uint16_t* __restrict__ Vt,
                                                int vld) {
    __shared__ __attribute__((aligned(16))) uint16_t Ks[16 * 512];
    __shared__ __attribute__((aligned(16))) uint16_t Vs[16 * 512];
    __shared__ __attribute__((aligned(16))) uint16_t Ps[4][32 * 88];

    const int tid = threadIdx.x, lane = tid & 63, w = tid >> 6;
    const int col = lane & 15, quad = lane >> 4;
    const int h = blockIdx.y & 15, b = blockIdx.y >> 4;
    const size_t brow = (size_t)b * SEQ;

    const uint16_t* kbase = Kp + brow * DMODEL + h * HD;
    const uint16_t* vtbase = Vt + (size_t)(h * HD) * vld + brow;
    const uint16_t* kg0 = kbase + (size_t)(w * 16 + col) * DMODEL + quad * 8;
    const uint16_t* vg0 = vtbase + (size_t)(w * 32 + col) * vld + quad * 8;

    for (int half = 0; half < 2; ++half) {
        const int qi = half ? (int)blockIdx.x : (15 - (int)blockIdx.x);
        const int q0 = qi * 128;
        uint16_t* qbase = QO + (brow + q0 + w * 32) * DMODEL + h * HD;

        bf16x8 qf[2][4];
#pragma unroll
        for (int i = 0; i < 2; i++)
#pragma unroll
            for (int kk = 0; kk < 4; kk++)
                qf[i][kk] = *(const bf16x8*)(qbase + (size_t)(i * 16 + col) * DMODEL +
                                             kk * 32 + quad * 8);

        floatx4 accO[2][8];
#pragma unroll
        for (int i = 0; i < 2; i++)
#pragma unroll
            for (int jd = 0; jd < 8; jd++) accO[i][jd] = (floatx4){0.f, 0.f, 0.f, 0.f};
        float mrun[2][4], lrun[2][4];
#pragma unroll
        for (int i = 0; i < 2; i++)
#pragma unroll
            for (int r = 0; r < 4; r++) { mrun[i][r] = -1e30f; lrun[i][r] = 0.f; }

        const int nkt = 2 * qi + 2;

        uint4 kv[4], vv4[4];
        {
#pragma unroll
            for (int p = 0; p < 4; p++)
                kv[p] = *(const uint4*)(kg0 + p * 32);
#pragma unroll
            for (int s = 0; s < 2; s++)
#pragma unroll
                for (int k2 = 0; k2 < 2; k2++)
                    vv4[s * 2 + k2] =
                        *(const uint4*)(vg0 + (size_t)s * 16 * vld + k2 * 32);
        }

        for (int ki = 0; ki < nkt; ki++) {
            const int key0 = ki * 64;
#pragma unroll
            for (int p = 0; p < 4; p++)
                *(uint4*)&Ks[(w * 4 + p) * 512 + lane * 8] = kv[p];
#pragma unroll
            for (int s = 0; s < 2; s++)
#pragma unroll
                for (int k2 = 0; k2 < 2; k2++)
                    *(uint4*)&Vs[((w * 2 + s) * 2 + k2) * 512 + lane * 8] =
                        vv4[s * 2 + k2];
            __syncthreads();

            if (ki + 1 < nkt) {
                const size_t koff = (size_t)(key0 + 64);
#pragma unroll
                for (int p = 0; p < 4; p++)
                    kv[p] = *(const uint4*)(kg0 + koff * DMODEL + p * 32);
#pragma unroll
                for (int s = 0; s < 2; s++)
#pragma unroll
                    for (int k2 = 0; k2 < 2; k2++)
                        vv4[s * 2 + k2] = *(const uint4*)(vg0 + (size_t)s * 16 * vld +
                                                          koff + k2 * 32);
            }

            floatx4 s[2][4];
            __builtin_amdgcn_s_setprio(1);
#pragma unroll
            for (int i = 0; i < 2; i++)
#pragma unroll
                for (int jk = 0; jk < 4; jk++) {
                    floatx4 a = (floatx4){0.f, 0.f, 0.f, 0.f};
#pragma unroll
                    for (int kk = 0; kk < 4; kk++) {
                        bf16x8 bb = *(const bf16x8*)&Ks[(jk * 4 + kk) * 512 + lane * 8];
                        a = __builtin_amdgcn_mfma_f32_16x16x32_bf16(qf[i][kk], bb, a, 0, 0, 0);
                    }
                    s[i][jk] = a;
                }
            __builtin_amdgcn_s_setprio(0);

            if (key0 + 63 > q0 + w * 32) {
#pragma unroll
                for (int i = 0; i < 2; i++) {
                    const int qb = q0 + w * 32 + i * 16 + quad * 4;
#pragma unroll
                    for (int jk = 0; jk < 4; jk++) {
                        const int key = key0 + jk * 16 + col;
#pragma unroll
                        for (int r = 0; r < 4; r++)
                            if (key > qb + r) s[i][jk][r] = -1e30f;
                    }
                }
            }

            float alpha[2][4];
#pragma unroll
            for (int i = 0; i < 2; i++)
#pragma unroll
                for (int r = 0; r < 4; r++) {
                    float mx = s[i][0][r];
#pragma unroll
                    for (int jk = 1; jk < 4; jk++) mx = fmaxf(mx, s[i][jk][r]);
                    mx = fmaxf(mx, __shfl_xor(mx, 1, 64));
                    mx = fmaxf(mx, __shfl_xor(mx, 2, 64));
                    mx = fmaxf(mx, __shfl_xor(mx, 4, 64));
                    mx = fmaxf(mx, __shfl_xor(mx, 8, 64));
                    mx = fmaxf(mx, mrun[i][r]);
                    alpha[i][r] = exp2f((mrun[i][r] - mx) * LOG2E);
                    mrun[i][r] = mx;
                }
#pragma unroll
            for (int i = 0; i < 2; i++)
#pragma unroll
                for (int r = 0; r < 4; r++) {
                    float psum = 0.f;
#pragma unroll
                    for (int jk = 0; jk < 4; jk++) {
                        const float p = exp2f((s[i][jk][r] - mrun[i][r]) * LOG2E);
                        psum += p;
                        Ps[w][(i * 16 + quad * 4 + r) * 88 + jk * 16 + col] = f2b(p);
                    }
                    lrun[i][r] = lrun[i][r] * alpha[i][r] + psum;
                }
#pragma unroll
            for (int i = 0; i < 2; i++)
#pragma unroll
                for (int jd = 0; jd < 8; jd++)
#pragma unroll
                    for (int r = 0; r < 4; r++) accO[i][jd][r] *= alpha[i][r];

            bf16x8 pf[2][2];
#pragma unroll
            for (int i = 0; i < 2; i++)
#pragma unroll
                for (int k2 = 0; k2 < 2; k2++)
                    pf[i][k2] = *(const bf16x8*)&Ps[w][(i * 16 + col) * 88 + k2 * 32 + quad * 8];
            __builtin_amdgcn_s_setprio(1);
#pragma unroll
            for (int jd = 0; jd < 8; jd++)
#pragma unroll
                for (int k2 = 0; k2 < 2; k2++) {
                    bf16x8 vvv = *(const bf16x8*)&Vs[(jd * 2 + k2) * 512 + lane * 8];
#pragma unroll
                    for (int i = 0; i < 2; i++)
                        accO[i][jd] = __builtin_amdgcn_mfma_f32_16x16x32_bf16(pf[i][k2], vvv,
                                                                              accO[i][jd], 0, 0, 0);
                }
            __builtin_amdgcn_s_setprio(0);
            __syncthreads();
        }

        float inv[2][4];
#pragma unroll
        for (int i = 0; i < 2; i++)
#pragma unroll
            for (int r = 0; r < 4; r++) {
                float l = lrun[i][r];
                l += __shfl_xor(l, 1, 64);
                l += __shfl_xor(l, 2, 64);
                l += __shfl_xor(l, 4, 64);
                l += __shfl_xor(l, 8, 64);
                inv[i][r] = 1.0f / l;
            }
#pragma unroll
        for (int i = 0; i < 2; i++)
#pragma unroll
            for (int jd = 0; jd < 8; jd++)
#pragma unroll
                for (int r = 0; r < 4; r++)
                    qbase[(size_t)(i * 16 + quad * 4 + r) * DMODEL + jd * 16 + col] =
                        f2b(accO[i][jd][r] * inv[i][r]);
    }
}

// ---------------------------------------------------------------------------
extern "C" void kernel_launch(void* const* d_in, const int* in_sizes, int n_in,
                              void* d_out, int out_size, void* d_ws, size_t ws_size,
                              hipStream_t stream) {
    const float* X   = (const float*)d_in[0];
    float*       msk = (float*)d_in[1];  // scratch in tiny-ws fallback
    const float* wq  = (const float*)d_in[2];
    const float* wqb = (const float*)d_in[3];
    const float* wk  = (const float*)d_in[4];
    const float* wkb = (const float*)d_in[5];
    const float* wv  = (const float*)d_in[6];
    const float* wvb = (const float*)d_in[7];
    const float* wo  = (const float*)d_in[8];
    const float* wob = (const float*)d_in[9];
    float* out = (float*)d_out;

    char* ws = (char*)d_ws;
    const size_t MB = 1ull << 20;
    dim3 tb(256), tb512(512), gT(32, 32);
    const float qs = 0.08838834764831845f;  // 1/sqrt(128)

    if (ws_size >= 136 * MB) {
        // ---- whole-problem path ----
        uint16_t* Xb = (uint16_t*)(ws);
        uint16_t* Qb = (uint16_t*)(ws + 32 * MB);
        uint16_t* Kb = (uint16_t*)(ws + 64 * MB);
        uint16_t* Vb = (uint16_t*)(ws + 96 * MB);  // holds Vt [2048][8192]
        uint16_t* Wt = (uint16_t*)(ws + 128 * MB);
        dim3 g256((MTOT / 256) * (DMODEL / 256));  // 256 blocks, 1/CU
        dim3 gF(8, 64);
        cvt_bf16<<<8192, tb, 0, stream>>>(X, Xb, MTOT * DMODEL);
        tr_wf<<<gT, tb, 0, stream>>>(wq, Wt);
        gemm256<<<g256, tb512, 0, stream>>>(Xb, Wt, wqb, Qb, qs, 0, 0);
        tr_wf<<<gT, tb, 0, stream>>>(wk, Wt);
        gemm256<<<g256, tb512, 0, stream>>>(Xb, Wt, wkb, Kb, 1.0f, 0, 0);
        tr_wf<<<gT, tb, 0, stream>>>(wv, Wt);
        gemm256<<<g256, tb512, 0, stream>>>(Xb, Wt, wvb, Vb, 1.0f, 2, MTOT);
        flash<<<gF, tb, 0, stream>>>(Qb, Kb, Vb, MTOT);  // ctx in-place over Q
        tr_wf<<<gT, tb, 0, stream>>>(wo, Wt);
        gemm256<<<g256, tb512, 0, stream>>>(Qb, Wt, wob, out, 1.0f, 1, 0);
    } else {
        // ---- per-batch paths (128-tile gemm kept here) ----
        uint16_t* Xb = (uint16_t*)(ws);
        uint16_t* Qb = (uint16_t*)(ws + 8 * MB);
        uint16_t *Kb, *Vb, *Wt;
        if (ws_size >= 40 * MB) {
            Kb = (uint16_t*)(ws + 16 * MB);
            Vb = (uint16_t*)(ws + 24 * MB);
            Wt = (uint16_t*)(ws + 32 * MB);
        } else {
            Kb = (uint16_t*)msk;
            Vb = Kb + (size_t)SEQ * DMODEL;
            Wt = (uint16_t*)(ws + 16 * MB);
        }
        dim3 gG(16, 16), gF(8, 16);
        for (int b = 0; b < BATCH; b++) {
            const float* Xf = X + (size_t)b * SEQ * DMODEL;
            float* Ob = out + (size_t)b * SEQ * DMODEL;
            cvt_bf16<<<2048, tb, 0, stream>>>(Xf, Xb, SEQ * DMODEL);
            tr_wf<<<gT, tb, 0, stream>>>(wq, Wt);
            gemm<<<gG, tb, 0, stream>>>(Xb, Wt, wqb, Qb, qs, 0, 0);
            tr_wf<<<gT, tb, 0, stream>>>(wk, Wt);
            gemm<<<gG, tb, 0, stream>>>(Xb, Wt, wkb, Kb, 1.0f, 0, 0);
            tr_wf<<<gT, tb, 0, stream>>>(wv, Wt);
            gemm<<<gG, tb, 0, stream>>>(Xb, Wt, wvb, Vb, 1.0f, 2, SEQ);
            flash<<<gF, tb, 0, stream>>>(Qb, Kb, Vb, SEQ);
            tr_wf<<<gT, tb, 0, stream>>>(wo, Wt);
            gemm<<<gG, tb, 0, stream>>>(Qb, Wt, wob, Ob, 1.0f, 1, 0);
        }
    }

    (void)in_sizes; (void)n_in; (void)out_size;
}